// Round 2
// baseline (2143.376 us; speedup 1.0000x reference)
//
#include <hip/hip_runtime.h>
#include <hip/hip_fp16.h>

typedef _Float16 f16;
typedef __attribute__((ext_vector_type(2))) _Float16 f16x2;
typedef __attribute__((ext_vector_type(2))) __fp16 h16x2;  // cvt_pkrtz native type
typedef __attribute__((ext_vector_type(8))) _Float16 f16x8;
typedef __attribute__((ext_vector_type(4))) float f32x4;

#define B_ 128
#define S_ 1024
#define I_ 768
#define H_ 256
#define O_ 6
#define G3 768  // 3*H

#if __has_builtin(__builtin_amdgcn_fdot2)
#define FDOT2(w, h, c) __builtin_amdgcn_fdot2((w), (h), (c), false)
#else
// fallback: should pattern-match to v_fma_mix_f32
#define FDOT2(w, h, c) ((c) + (float)(w)[0] * (float)(h)[0] + (float)(w)[1] * (float)(h)[1])
#endif

// ---------------------------------------------------------------------------
// prep: decay factors D[b,t], W_ih -> fp16, W_hh -> per-thread packed layout
// Wp layout for (unit, k-quarter) recur partition, 1024 threads:
//   thread tid = (i = tid&255, kq = tid>>8), wr[g*32+j] covers
//   W_hh[g*256+i][64*kq + 2j .. +2j+1]  =>  Wp[(g*32+j)*1024 + tid]
// ---------------------------------------------------------------------------
__global__ __launch_bounds__(256) void prep_kernel(
    const float* __restrict__ rel, const float* __restrict__ alpha,
    const float* __restrict__ Wih, const float* __restrict__ Whh,
    float* __restrict__ D, f16* __restrict__ WihH, unsigned* __restrict__ Wp) {
  int i = blockIdx.x * 256 + threadIdx.x;
  const int nD = B_ * S_;       // 131072
  const int nW = G3 * I_;       // 589824
  const int nP = 96 * 1024;     // 98304
  if (i < nD) {
    int t = i & (S_ - 1);
    float dt = t ? (rel[i] - rel[i - 1]) : rel[i];
    D[i] = __expf(-fabsf(alpha[0]) * dt);
  } else if (i < nD + nW) {
    int j = i - nD;
    WihH[j] = (f16)Wih[j];
  } else if (i < nD + nW + nP) {
    int k = i - nD - nW;
    int tid = k & 1023;
    int kidx = k >> 10;          // 0..95
    int g = kidx >> 5, j = kidx & 31;
    int ii = tid & 255, kq = tid >> 8;
    int row = g * H_ + ii;
    int c = 64 * kq + 2 * j;
    union { unsigned u32; f16 h[2]; } pk;
    pk.h[0] = (f16)Whh[row * H_ + c];
    pk.h[1] = (f16)Whh[row * H_ + c + 1];
    Wp[k] = pk.u32;
  }
}

// ---------------------------------------------------------------------------
// gemm_xg: XG[m][n] = sum_k x[m][k] * W_ih[n][k] + b_ih[n], fp16 out
// 128x128x32 tiles, 4 waves (2x2), 16 MFMA 16x16x32_f16 per wave per K-iter
// ---------------------------------------------------------------------------
__global__ __launch_bounds__(256) void gemm_xg(
    const float* __restrict__ X, const f16* __restrict__ Wh,
    const float* __restrict__ bih, f16* __restrict__ XG) {
  __shared__ f16 As[128 * 40];  // padded stride 40 halves
  __shared__ f16 Bs[128 * 32];
  int bid = blockIdx.x;
  int nt = bid % 6, mt = bid / 6;  // nt fast -> A-tile L2 reuse
  int m0 = mt * 128, n0 = nt * 128;
  int tid = threadIdx.x, w = tid >> 6, lane = tid & 63;
  int wm = (w & 1) * 64, wn = (w >> 1) * 64;
  f32x4 acc[16];
#pragma unroll
  for (int i = 0; i < 16; i++) acc[i] = (f32x4){0.f, 0.f, 0.f, 0.f};
  int ar = tid >> 1, ah = tid & 1;  // A stage: row, 16-col half
  const float* aptr = X + (size_t)(m0 + ar) * I_ + ah * 16;
  int br = tid >> 1, bh = tid & 1;  // B stage: row, 16-col half

  for (int kk = 0; kk < 24; kk++) {
    int k0 = kk * 32;
    // ---- stage A (fp32 -> fp16 convert) ----
    const float4* af4 = (const float4*)(aptr + k0);
    float4 f0 = af4[0], f1 = af4[1], f2 = af4[2], f3 = af4[3];
    union { h16x2 h2[4]; uint4 v; } pa, pb;
    pa.h2[0] = __builtin_amdgcn_cvt_pkrtz(f0.x, f0.y);
    pa.h2[1] = __builtin_amdgcn_cvt_pkrtz(f0.z, f0.w);
    pa.h2[2] = __builtin_amdgcn_cvt_pkrtz(f1.x, f1.y);
    pa.h2[3] = __builtin_amdgcn_cvt_pkrtz(f1.z, f1.w);
    pb.h2[0] = __builtin_amdgcn_cvt_pkrtz(f2.x, f2.y);
    pb.h2[1] = __builtin_amdgcn_cvt_pkrtz(f2.z, f2.w);
    pb.h2[2] = __builtin_amdgcn_cvt_pkrtz(f3.x, f3.y);
    pb.h2[3] = __builtin_amdgcn_cvt_pkrtz(f3.z, f3.w);
    *(uint4*)&As[ar * 40 + ah * 16] = pa.v;
    *(uint4*)&As[ar * 40 + ah * 16 + 8] = pb.v;
    // ---- stage B (already fp16) ----
    const uint4* bg = (const uint4*)(Wh + (size_t)(n0 + br) * I_ + k0 + bh * 16);
    uint4 b0 = bg[0], b1 = bg[1];
    *(uint4*)&Bs[br * 32 + bh * 16] = b0;
    *(uint4*)&Bs[br * 32 + bh * 16 + 8] = b1;
    __syncthreads();
    // ---- fragments + MFMA ----
    int quad = lane >> 4, r16 = lane & 15;
    f16x8 afr[4], bfr[4];
#pragma unroll
    for (int m = 0; m < 4; m++)
      afr[m] = *(const f16x8*)&As[(wm + m * 16 + r16) * 40 + quad * 8];
#pragma unroll
    for (int n = 0; n < 4; n++)
      bfr[n] = *(const f16x8*)&Bs[(wn + n * 16 + r16) * 32 + quad * 8];
#pragma unroll
    for (int m = 0; m < 4; m++)
#pragma unroll
      for (int n = 0; n < 4; n++)
        acc[m * 4 + n] = __builtin_amdgcn_mfma_f32_16x16x32_f16(
            afr[m], bfr[n], acc[m * 4 + n], 0, 0, 0);
    __syncthreads();
  }
  // ---- epilogue: C/D layout col=lane&15, row=(lane>>4)*4+reg ----
  int col = lane & 15, rb = (lane >> 4) * 4;
#pragma unroll
  for (int n = 0; n < 4; n++) {
    int gn = n0 + wn + n * 16 + col;
    float bv = bih[gn];
#pragma unroll
    for (int m = 0; m < 4; m++) {
      f32x4 a = acc[m * 4 + n];
      int gm0 = m0 + wm + m * 16 + rb;
#pragma unroll
      for (int r = 0; r < 4; r++)
        XG[(size_t)(gm0 + r) * G3 + gn] = (f16)(a[r] + bv);
    }
  }
}

// ---------------------------------------------------------------------------
// recur: one wg per (batch, seq-half), 1024 threads (16 waves, 4/SIMD).
// Partition: thread = (unit i = tid&255, k-quarter kq = tid>>8). kq is
// wave-uniform (waves 0-3=kq0 ... 12-15=kq3), so the readlane h-broadcast
// stays legal: hv holds this wave's 32 half2; 32 readlanes feed 96 fdot2.
// wr shrinks to 96 regs -> wave fits in 128 VGPRs -> 4 waves/SIMD resident,
// doubling latency hiding vs the 2-way split. Exchange: kq!=0 write 3 floats
// at consecutive addresses; kq=0 (one wave per SIMD) sums 4 quarters and
// finishes all 3 gates. XG prefetched 2 steps ahead (slack >> HBM latency).
// ---------------------------------------------------------------------------
__global__ __launch_bounds__(1024, 4) void recur_kernel(
    const f16* __restrict__ XG, const unsigned* __restrict__ Wp,
    const float* __restrict__ D, const float* __restrict__ bhh,
    f16* __restrict__ HS) {
  __shared__ float part[3 * 4 * 256];  // [g][kq][i], i consecutive
  __shared__ unsigned h_pk[2][128];    // double-buffered h as half2
  __shared__ float Ds[576];
  __shared__ float bhs[G3];
  int bx = blockIdx.x;
  int b = bx >> 1, seg = bx & 1;
  const int t0 = seg ? 448 : 0;    // 128-step burn-in for seg1
  const int t1 = seg ? 1024 : 576;
  const int ts = seg ? 576 : 0;
  int tid = threadIdx.x, lane = tid & 63;
  int i = tid & 255, kq = tid >> 8;
  unsigned wr[96];
#pragma unroll
  for (int k = 0; k < 96; k++) wr[k] = Wp[k * 1024 + tid];
  if (tid < 576) Ds[tid] = D[b * S_ + t0 + tid];
  if (tid < G3) bhs[tid] = bhh[tid];
  if (tid < 128) h_pk[0][tid] = 0u;  // t0 even for both segs -> buf 0
  float hreg = 0.f;
  const bool own = (kq == 0);
  float xr = 0.f, xz = 0.f, xn = 0.f;    // gate inputs for step t
  float nxr = 0.f, nxz = 0.f, nxn = 0.f; // prefetched for step t+1
  if (own) {
    const f16* p0 = XG + ((size_t)b * S_ + t0) * G3;
    xr = (float)p0[i]; xz = (float)p0[H_ + i]; xn = (float)p0[2 * H_ + i];
    const f16* p1 = p0 + G3;
    nxr = (float)p1[i]; nxz = (float)p1[H_ + i]; nxn = (float)p1[2 * H_ + i];
  }
  __syncthreads();

  for (int t = t0; t < t1; t++) {
    unsigned hv = h_pk[t & 1][(kq << 5) + (lane & 31)];  // 2-way bcast, free
    float a0 = 0.f, a1 = 0.f, a2 = 0.f, a3 = 0.f, a4 = 0.f, a5 = 0.f;
#pragma unroll
    for (int j = 0; j < 32; j += 2) {
      int s0 = __builtin_amdgcn_readlane((int)hv, j);
      int s1 = __builtin_amdgcn_readlane((int)hv, j + 1);
      union { int i32; f16x2 h; } c0, c1;
      c0.i32 = s0; c1.i32 = s1;
      union { unsigned u32; f16x2 h; } w0, w1, w2, w3, w4, w5;
      w0.u32 = wr[j];       w1.u32 = wr[32 + j];     w2.u32 = wr[64 + j];
      w3.u32 = wr[j + 1];   w4.u32 = wr[32 + j + 1]; w5.u32 = wr[64 + j + 1];
      a0 = FDOT2(w0.h, c0.h, a0);
      a1 = FDOT2(w1.h, c0.h, a1);
      a2 = FDOT2(w2.h, c0.h, a2);
      a3 = FDOT2(w3.h, c1.h, a3);
      a4 = FDOT2(w4.h, c1.h, a4);
      a5 = FDOT2(w5.h, c1.h, a5);
    }
    float pr = a0 + a3, pz = a1 + a4, pn = a2 + a5;
    if (!own) {  // wave-uniform; consecutive addresses, conflict-free
      part[(0 * 4 + kq) * 256 + i] = pr;
      part[(1 * 4 + kq) * 256 + i] = pz;
      part[(2 * 4 + kq) * 256 + i] = pn;
    }
    __syncthreads();
    if (own) {  // waves 0-3: exactly one owner wave per SIMD
      float Dt = Ds[t - t0];
      // decay commutes with the matvec: hg = (D*h) @ W^T = D * (h @ W^T)
      float hr = (pr + part[1 * 256 + i] + part[2 * 256 + i] + part[3 * 256 + i]) * Dt + bhs[i];
      float hz = (pz + part[(4 + 1) * 256 + i] + part[(4 + 2) * 256 + i] + part[(4 + 3) * 256 + i]) * Dt + bhs[H_ + i];
      float hn = (pn + part[(8 + 1) * 256 + i] + part[(8 + 2) * 256 + i] + part[(8 + 3) * 256 + i]) * Dt + bhs[2 * H_ + i];
      float r = 1.f / (1.f + __expf(-(xr + hr)));
      float z = 1.f / (1.f + __expf(-(xz + hz)));
      float pre = xn + r * hn;
      float e = __expf(-2.f * pre);
      float nn = (1.f - e) / (1.f + e);  // tanh
      hreg = (1.f - z) * nn + z * (hreg * Dt);
      f16 h16 = (f16)hreg;
      ((f16*)h_pk[(t + 1) & 1])[i] = h16;  // ds_write_b16, disjoint halves
      if (t >= ts) HS[(size_t)(b * S_ + t) * H_ + i] = h16;  // from register
      xr = nxr; xz = nxz; xn = nxn;  // rotate pipeline
      if (t + 2 < t1) {  // prefetch t+2: slack of 2 steps >> HBM latency
        const f16* p2 = XG + ((size_t)b * S_ + (t + 2)) * G3;
        nxr = (float)p2[i]; nxz = (float)p2[H_ + i]; nxn = (float)p2[2 * H_ + i];
      }
    }
    __syncthreads();
  }
}

// ---------------------------------------------------------------------------
// fc: out[r][o] = hs[r][:] . W_fc[o][:] + b_fc[o]; one wave per row
// ---------------------------------------------------------------------------
__global__ __launch_bounds__(256) void fc_kernel(
    const f16* __restrict__ HS, const float* __restrict__ Wfc,
    const float* __restrict__ bfc, float* __restrict__ OUT) {
  int tid = threadIdx.x, wv = tid >> 6, lane = tid & 63;
  int gw = blockIdx.x * 4 + wv;  // 2048 waves total
  float wreg[6][4];
#pragma unroll
  for (int o = 0; o < 6; o++)
#pragma unroll
    for (int c = 0; c < 4; c++) wreg[o][c] = Wfc[o * H_ + lane * 4 + c];
  for (int r = gw; r < B_ * S_; r += 2048) {
    union { uint2 v; f16 h[4]; } cv;
    cv.v = *(const uint2*)(HS + (size_t)r * H_ + lane * 4);
    float h0 = (float)cv.h[0], h1 = (float)cv.h[1];
    float h2 = (float)cv.h[2], h3 = (float)cv.h[3];
    float s[6];
#pragma unroll
    for (int o = 0; o < 6; o++)
      s[o] = h0 * wreg[o][0] + h1 * wreg[o][1] + h2 * wreg[o][2] + h3 * wreg[o][3];
#pragma unroll
    for (int m = 1; m < 64; m <<= 1)
#pragma unroll
      for (int o = 0; o < 6; o++) s[o] += __shfl_xor(s[o], m, 64);
    if (lane == 0)
#pragma unroll
      for (int o = 0; o < 6; o++) OUT[(size_t)r * O_ + o] = s[o] + bfc[o];
  }
}

// ---------------------------------------------------------------------------
extern "C" void kernel_launch(void* const* d_in, const int* in_sizes, int n_in,
                              void* d_out, int out_size, void* d_ws, size_t ws_size,
                              hipStream_t stream) {
  const float* x     = (const float*)d_in[0];
  const float* rel   = (const float*)d_in[1];
  const float* alpha = (const float*)d_in[2];
  const float* Wih   = (const float*)d_in[3];
  const float* bih   = (const float*)d_in[4];
  const float* Whh   = (const float*)d_in[5];
  const float* bhh   = (const float*)d_in[6];
  const float* Wfc   = (const float*)d_in[7];
  const float* bfc   = (const float*)d_in[8];
  float* out = (float*)d_out;
  char* ws = (char*)d_ws;
  // workspace layout (~258 MB total)
  f16* XG       = (f16*)(ws);                     // 201326592 B  [B*S,768] fp16
  f16* HS       = (f16*)(ws + 201326592);         //  67108864 B  [B*S,256] fp16
  float* D      = (float*)(ws + 268435456);       //    524288 B  [B,S]
  f16* WihH     = (f16*)(ws + 268959744);         //   1179648 B
  unsigned* Wp  = (unsigned*)(ws + 270139392);    //    393216 B
  prep_kernel<<<3200, 256, 0, stream>>>(rel, alpha, Wih, Whh, D, WihH, Wp);
  gemm_xg<<<6144, 256, 0, stream>>>(x, WihH, bih, XG);
  recur_kernel<<<256, 1024, 0, stream>>>(XG, Wp, D, bhh, HS);
  fc_kernel<<<512, 256, 0, stream>>>(HS, Wfc, bfc, out);
}

// Round 3
// 1827.743 us; speedup vs baseline: 1.1727x; 1.1727x over previous
//
#include <hip/hip_runtime.h>
#include <hip/hip_fp16.h>

typedef _Float16 f16;
typedef __attribute__((ext_vector_type(2))) _Float16 f16x2;
typedef __attribute__((ext_vector_type(2))) __fp16 h16x2;  // cvt_pkrtz native type
typedef __attribute__((ext_vector_type(8))) _Float16 f16x8;
typedef __attribute__((ext_vector_type(4))) float f32x4;

#define B_ 128
#define S_ 1024
#define I_ 768
#define H_ 256
#define O_ 6
#define G3 768  // 3*H

// recur geometry
#define NSEG 16
#define SEGLEN 64    // S_/NSEG
#define BURN 128     // validated burn-in (contractive: (z*D)^128 << fp16 floor)
#define MAXSTEP 192  // SEGLEN+BURN
#define XGROW 792    // padded halves per xg LDS row (1584 B = 396 dw ≡ 12 mod 32)
#define DSROW 193    // Ds row stride (banks spread)

// async global->LDS, 16B per lane; lds dest must be lane-linear
__device__ __forceinline__ void gl_lds16(const void* g, void* l) {
#if __has_builtin(__builtin_amdgcn_global_load_lds)
  __builtin_amdgcn_global_load_lds(
      (const __attribute__((address_space(1))) unsigned*)g,
      (__attribute__((address_space(3))) unsigned*)l, 16, 0, 0);
#else
  *(uint4*)l = *(const uint4*)g;
#endif
}

// ---------------------------------------------------------------------------
// prep: decay factors D[b,t]; W_ih -> fp16; W_hh -> fp16 flat [768][256]
// ---------------------------------------------------------------------------
__global__ __launch_bounds__(256) void prep_kernel(
    const float* __restrict__ rel, const float* __restrict__ alpha,
    const float* __restrict__ Wih, const float* __restrict__ Whh,
    float* __restrict__ D, f16* __restrict__ WihH, f16* __restrict__ WhhH) {
  int i = blockIdx.x * 256 + threadIdx.x;
  const int nD = B_ * S_;     // 131072
  const int nW = G3 * I_;     // 589824
  const int nWh = G3 * H_;    // 196608
  if (i < nD) {
    int t = i & (S_ - 1);
    float dt = t ? (rel[i] - rel[i - 1]) : rel[i];
    D[i] = __expf(-fabsf(alpha[0]) * dt);
  } else if (i < nD + nW) {
    int j = i - nD;
    WihH[j] = (f16)Wih[j];
  } else if (i < nD + nW + nWh) {
    int j = i - nD - nW;
    WhhH[j] = (f16)Whh[j];
  }
}

// ---------------------------------------------------------------------------
// gemm_xg: XG_T[t][b][n] = sum_k x[b,t,k] * W_ih[n][k] + b_ih[n], fp16 out
// (time-major output so recur's per-step 16-batch tile is contiguous)
// ---------------------------------------------------------------------------
__global__ __launch_bounds__(256) void gemm_xg(
    const float* __restrict__ X, const f16* __restrict__ Wh,
    const float* __restrict__ bih, f16* __restrict__ XG) {
  __shared__ f16 As[128 * 40];  // padded stride 40 halves
  __shared__ f16 Bs[128 * 32];
  int bid = blockIdx.x;
  int nt = bid % 6, mt = bid / 6;  // nt fast -> A-tile L2 reuse
  int m0 = mt * 128, n0 = nt * 128;
  int tid = threadIdx.x, w = tid >> 6, lane = tid & 63;
  int wm = (w & 1) * 64, wn = (w >> 1) * 64;
  f32x4 acc[16];
#pragma unroll
  for (int i = 0; i < 16; i++) acc[i] = (f32x4){0.f, 0.f, 0.f, 0.f};
  int ar = tid >> 1, ah = tid & 1;
  const float* aptr = X + (size_t)(m0 + ar) * I_ + ah * 16;
  int br = tid >> 1, bh = tid & 1;

  for (int kk = 0; kk < 24; kk++) {
    int k0 = kk * 32;
    const float4* af4 = (const float4*)(aptr + k0);
    float4 f0 = af4[0], f1 = af4[1], f2 = af4[2], f3 = af4[3];
    union { h16x2 h2[4]; uint4 v; } pa, pb;
    pa.h2[0] = __builtin_amdgcn_cvt_pkrtz(f0.x, f0.y);
    pa.h2[1] = __builtin_amdgcn_cvt_pkrtz(f0.z, f0.w);
    pa.h2[2] = __builtin_amdgcn_cvt_pkrtz(f1.x, f1.y);
    pa.h2[3] = __builtin_amdgcn_cvt_pkrtz(f1.z, f1.w);
    pb.h2[0] = __builtin_amdgcn_cvt_pkrtz(f2.x, f2.y);
    pb.h2[1] = __builtin_amdgcn_cvt_pkrtz(f2.z, f2.w);
    pb.h2[2] = __builtin_amdgcn_cvt_pkrtz(f3.x, f3.y);
    pb.h2[3] = __builtin_amdgcn_cvt_pkrtz(f3.z, f3.w);
    *(uint4*)&As[ar * 40 + ah * 16] = pa.v;
    *(uint4*)&As[ar * 40 + ah * 16 + 8] = pb.v;
    const uint4* bg = (const uint4*)(Wh + (size_t)(n0 + br) * I_ + k0 + bh * 16);
    uint4 b0 = bg[0], b1 = bg[1];
    *(uint4*)&Bs[br * 32 + bh * 16] = b0;
    *(uint4*)&Bs[br * 32 + bh * 16 + 8] = b1;
    __syncthreads();
    int quad = lane >> 4, r16 = lane & 15;
    f16x8 afr[4], bfr[4];
#pragma unroll
    for (int m = 0; m < 4; m++)
      afr[m] = *(const f16x8*)&As[(wm + m * 16 + r16) * 40 + quad * 8];
#pragma unroll
    for (int n = 0; n < 4; n++)
      bfr[n] = *(const f16x8*)&Bs[(wn + n * 16 + r16) * 32 + quad * 8];
#pragma unroll
    for (int m = 0; m < 4; m++)
#pragma unroll
      for (int n = 0; n < 4; n++)
        acc[m * 4 + n] = __builtin_amdgcn_mfma_f32_16x16x32_f16(
            afr[m], bfr[n], acc[m * 4 + n], 0, 0, 0);
    __syncthreads();
  }
  // epilogue: C/D layout col=lane&15, row=(lane>>4)*4+reg; store time-major
  int col = lane & 15, rb = (lane >> 4) * 4;
#pragma unroll
  for (int n = 0; n < 4; n++) {
    int gn = n0 + wn + n * 16 + col;
    float bv = bih[gn];
#pragma unroll
    for (int m = 0; m < 4; m++) {
      f32x4 a = acc[m * 4 + n];
      int gm0 = m0 + wm + m * 16 + rb;
#pragma unroll
      for (int r = 0; r < 4; r++) {
        int gm = gm0 + r;                        // gm = b*S + t
        size_t row = (size_t)((gm & (S_ - 1)) * B_ + (gm >> 10));  // t*128+b
        XG[row * G3 + gn] = (f16)(a[r] + bv);
      }
    }
  }
}

// ---------------------------------------------------------------------------
// recur (MFMA): one wg per (batch-group of 16, seq-segment). 512 thr, 8 waves.
// Per step: HG[16,768] = h[16,256] @ W_hh^T via 16x16x32_f16 MFMA.
// Wave w owns col-tiles {g*16+2w, g*16+2w+1} (g=0..2) -> its lanes hold
// matched (r,z,n) values for units U=32w+16qp+(lane&15), batches
// m=(lane>>4)*4+r -> gate math fully lane-parallel, no cross-wave exchange.
// W_hh B-fragments register-resident: 6 tiles x 8 K-frags x f16x8 = 192 regs.
// h double-buffered in LDS in fragment-linear order (addr=kt*1024+lane*16,
// conflict-free b128 reads). XG_T tile (24KB/step) staged one step ahead via
// global_load_lds into padded rows (4-way max conflicts on u16 gate reads).
// One barrier per step. 16 segments x 128-step burn-in.
// ---------------------------------------------------------------------------
__global__ __launch_bounds__(512, 2) void recur_kernel(
    const f16* __restrict__ XGT, const f16* __restrict__ WhhH,
    const float* __restrict__ D, const float* __restrict__ bhh,
    f16* __restrict__ HS) {
  __shared__ f16 xgb[2][12800];   // 2 x 25600 B (16 rows x 1584 B + pad)
  __shared__ f16 hb[2][4096];     // 2 x 8192 B, fragment-linear
  __shared__ float Ds[16 * DSROW];
  int bx = blockIdx.x;
  int bg = bx >> 4, s = bx & 15;
  const int ts = s * SEGLEN;
  const int t0 = (ts > BURN) ? ts - BURN : 0;
  const int t1 = ts + SEGLEN;
  int tid = threadIdx.x, w = tid >> 6, lane = tid & 63;
  int c = lane & 15, qd = lane >> 4;

  // W_hh B-fragments: lane holds W[T*16+c][kt*32+qd*8 .. +8]
  f16x8 wf[3][2][8];
#pragma unroll
  for (int g = 0; g < 3; g++)
#pragma unroll
    for (int qp = 0; qp < 2; qp++) {
      int T = g * 16 + 2 * w + qp;
#pragma unroll
      for (int kt = 0; kt < 8; kt++)
        wf[g][qp][kt] =
            *(const f16x8*)&WhhH[(size_t)(T * 16 + c) * H_ + kt * 32 + qd * 8];
    }
  float bh[3][2];
#pragma unroll
  for (int g = 0; g < 3; g++)
#pragma unroll
    for (int qp = 0; qp < 2; qp++)
      bh[g][qp] = bhh[g * H_ + 32 * w + 16 * qp + c];
  const int nst = t1 - t0;
  for (int idx = tid; idx < 16 * MAXSTEP; idx += 512) {
    int m = idx / MAXSTEP, tt = idx - m * MAXSTEP;
    if (tt < nst) Ds[m * DSROW + tt] = D[(bg * 16 + m) * S_ + t0 + tt];
  }
  for (int idx = tid; idx < 4096; idx += 512) hb[0][idx] = (f16)0.f;  // t0 even
  // stage-slot -> global-chunk mapping (row pad handled by clamp)
  int coff[4];
#pragma unroll
  for (int k = 0; k < 4; k++) {
    int slot = k * 512 + tid;
    int m = slot / 99;
    int v = slot - m * 99;
    if (m > 15) { m = 15; v = 95; }
    if (v > 95) v = 95;
    coff[k] = (m * 96 + v) * 16;
  }
  const char* xsrc0 = (const char*)XGT + (size_t)bg * 24576;
  {  // prologue: stage tile t0 into xgb[0]
    const char* src = xsrc0 + (size_t)t0 * 196608;
#pragma unroll
    for (int k = 0; k < 3; k++)
      gl_lds16(src + coff[k], (char*)&xgb[0][0] + (k * 512 + tid) * 16);
    if (tid < 64) gl_lds16(src + coff[3], (char*)&xgb[0][0] + (1536 + tid) * 16);
  }
  float hreg[2][4] = {};
  __syncthreads();

  for (int t = t0; t < t1; t++) {
    int nb = t & 1, tt = t - t0;
    if (t + 1 < t1) {  // stage next tile; lands during MFMA+gates
      const char* src = xsrc0 + (size_t)(t + 1) * 196608;
#pragma unroll
      for (int k = 0; k < 3; k++)
        gl_lds16(src + coff[k], (char*)&xgb[nb ^ 1][0] + (k * 512 + tid) * 16);
      if (tid < 64)
        gl_lds16(src + coff[3], (char*)&xgb[nb ^ 1][0] + (1536 + tid) * 16);
    }
    f32x4 acc[3][2];
#pragma unroll
    for (int g = 0; g < 3; g++)
#pragma unroll
      for (int qp = 0; qp < 2; qp++) acc[g][qp] = (f32x4){0.f, 0.f, 0.f, 0.f};
#pragma unroll
    for (int kt = 0; kt < 8; kt++) {
      f16x8 av = *(const f16x8*)&hb[nb][kt * 512 + lane * 8];
#pragma unroll
      for (int g = 0; g < 3; g++)
#pragma unroll
        for (int qp = 0; qp < 2; qp++)
          acc[g][qp] = __builtin_amdgcn_mfma_f32_16x16x32_f16(
              av, wf[g][qp][kt], acc[g][qp], 0, 0, 0);
    }
    // gates: all 512 lanes active, 8 (m,U) pairs each
    const f16* xg = xgb[nb];
    f16* hout = hb[nb ^ 1];
    bool st = (t >= ts);
#pragma unroll
    for (int qp = 0; qp < 2; qp++) {
      int U = 32 * w + 16 * qp + c;
#pragma unroll
      for (int r = 0; r < 4; r++) {
        int m = qd * 4 + r;
        float Dt = Ds[m * DSROW + tt];
        float xr = (float)xg[m * XGROW + U];
        float xz = (float)xg[m * XGROW + H_ + U];
        float xn = (float)xg[m * XGROW + 2 * H_ + U];
        // decay commutes with the matvec: hg = (D*h)@W^T = D*(h@W^T)
        float hr = acc[0][qp][r] * Dt + bh[0][qp];
        float hz = acc[1][qp][r] * Dt + bh[1][qp];
        float hv = acc[2][qp][r] * Dt + bh[2][qp];
        float rg = 1.f / (1.f + __expf(-(xr + hr)));
        float zg = 1.f / (1.f + __expf(-(xz + hz)));
        float pre = xn + rg * hv;
        float e2 = __expf(-2.f * pre);
        float nn = (1.f - e2) / (1.f + e2);  // tanh
        float hnew = (1.f - zg) * nn + zg * (hreg[qp][r] * Dt);
        hreg[qp][r] = hnew;
        f16 h16 = (f16)hnew;
        // fragment-linear store for next step's A: u=32w+16qp+c
        hout[(((w * 4 + 2 * qp + (c >> 3)) * 16 + m) << 3) + (c & 7)] = h16;
        if (st) HS[((size_t)(bg * 16 + m) * S_ + t) * H_ + U] = h16;
      }
    }
    __syncthreads();  // h writes + staged DMA visible for step t+1
  }
}

// ---------------------------------------------------------------------------
// fc: out[r][o] = hs[r][:] . W_fc[o][:] + b_fc[o]; one wave per row
// ---------------------------------------------------------------------------
__global__ __launch_bounds__(256) void fc_kernel(
    const f16* __restrict__ HS, const float* __restrict__ Wfc,
    const float* __restrict__ bfc, float* __restrict__ OUT) {
  int tid = threadIdx.x, wv = tid >> 6, lane = tid & 63;
  int gw = blockIdx.x * 4 + wv;  // 2048 waves total
  float wreg[6][4];
#pragma unroll
  for (int o = 0; o < 6; o++)
#pragma unroll
    for (int c = 0; c < 4; c++) wreg[o][c] = Wfc[o * H_ + lane * 4 + c];
  for (int r = gw; r < B_ * S_; r += 2048) {
    union { uint2 v; f16 h[4]; } cv;
    cv.v = *(const uint2*)(HS + (size_t)r * H_ + lane * 4);
    float h0 = (float)cv.h[0], h1 = (float)cv.h[1];
    float h2 = (float)cv.h[2], h3 = (float)cv.h[3];
    float s[6];
#pragma unroll
    for (int o = 0; o < 6; o++)
      s[o] = h0 * wreg[o][0] + h1 * wreg[o][1] + h2 * wreg[o][2] + h3 * wreg[o][3];
#pragma unroll
    for (int m = 1; m < 64; m <<= 1)
#pragma unroll
      for (int o = 0; o < 6; o++) s[o] += __shfl_xor(s[o], m, 64);
    if (lane == 0)
#pragma unroll
      for (int o = 0; o < 6; o++) OUT[(size_t)r * O_ + o] = s[o] + bfc[o];
  }
}

// ---------------------------------------------------------------------------
extern "C" void kernel_launch(void* const* d_in, const int* in_sizes, int n_in,
                              void* d_out, int out_size, void* d_ws, size_t ws_size,
                              hipStream_t stream) {
  const float* x     = (const float*)d_in[0];
  const float* rel   = (const float*)d_in[1];
  const float* alpha = (const float*)d_in[2];
  const float* Wih   = (const float*)d_in[3];
  const float* bih   = (const float*)d_in[4];
  const float* Whh   = (const float*)d_in[5];
  const float* bhh   = (const float*)d_in[6];
  const float* Wfc   = (const float*)d_in[7];
  const float* bfc   = (const float*)d_in[8];
  float* out = (float*)d_out;
  char* ws = (char*)d_ws;
  // workspace layout (~258 MB total)
  f16* XGT      = (f16*)(ws);                     // 201326592 B  [S,B,768] fp16
  f16* HS       = (f16*)(ws + 201326592);         //  67108864 B  [B,S,256] fp16
  float* D      = (float*)(ws + 268435456);       //    524288 B  [B,S]
  f16* WihH     = (f16*)(ws + 268959744);         //   1179648 B
  f16* WhhH     = (f16*)(ws + 270139392);         //    393216 B  [768,256] fp16
  prep_kernel<<<3584, 256, 0, stream>>>(rel, alpha, Wih, Whh, D, WihH, WhhH);
  gemm_xg<<<6144, 256, 0, stream>>>(x, WihH, bih, XGT);
  recur_kernel<<<128, 512, 0, stream>>>(XGT, WhhH, D, bhh, HS);
  fc_kernel<<<512, 256, 0, stream>>>(HS, Wfc, bfc, out);
}